// Round 7
// baseline (158.041 us; speedup 1.0000x reference)
//
#include <hip/hip_runtime.h>
#include <hip/hip_cooperative_groups.h>

namespace cg = cooperative_groups;

#define NNODES 1024
#define NHEADS 8
#define NHID 16
#define DIM 128            // NHEADS * NHID
#define NEG_SLOPE 0.2f

// One cooperative kernel: stage 1 = projection (2 nodes per block),
// grid-wide sync, stage 2 = fused triple-softmax + aggregation (R4 body).
__global__ __launch_bounds__(256, 2) void gat_kernel(
    const float* __restrict__ hfeat, const int* __restrict__ adj,
    const float* __restrict__ s, const float* __restrict__ W,
    const float* __restrict__ attn_w,
    float* __restrict__ g, float* __restrict__ dstv,
    float* __restrict__ out)
{
    const int i0   = blockIdx.x * 2;
    const int tid  = threadIdx.x;
    const int lane = tid & 63;
    const int wv   = tid >> 6;            // wave 0..3

    __shared__ float hs[2][DIM];          // 1 KB
    __shared__ float sh_src[2][NHEADS];
    __shared__ float evL[2][NNODES];      // 8 KB
    __shared__ float zeA[4][NHEADS][2];
    __shared__ float zsA[4][2];
    __shared__ float statE[2][NHEADS];
    __shared__ float statS[2];
    __shared__ float redO[4][2][NHEADS][16];  // 4 KB
    __shared__ float ztA[4][2][NHEADS];

    // ================= Stage 1: projection for nodes i0, i0+1 =================
    {
        const int r1 = tid >> 7;          // row 0/1
        const int o  = tid & 127;         // output feature
        hs[r1][o] = hfeat[(size_t)(i0 + r1) * DIM + o];
        __syncthreads();
        const float4* hv = (const float4*)hs[r1];
        const float4* wrow = (const float4*)(W + (size_t)o * DIM);
        float acc = 0.f;
#pragma unroll
        for (int k = 0; k < DIM / 4; k++) {
            float4 a = hv[k]; float4 b = wrow[k];
            acc = fmaf(a.x, b.x, fmaf(a.y, b.y, fmaf(a.z, b.z, fmaf(a.w, b.w, acc))));
        }
        g[(size_t)(i0 + r1) * DIM + o] = acc;
        const int f  = o & (NHID - 1);
        const int hd = o >> 4;
        float sv = acc * attn_w[f];
        float dv = acc * attn_w[NHID + f];
#pragma unroll
        for (int off = 8; off > 0; off >>= 1) {   // reduce within 16-lane head group
            sv += __shfl_xor(sv, off, 64);
            dv += __shfl_xor(dv, off, 64);
        }
        if (f == 0) {
            sh_src[r1][hd] = sv;                         // only this block needs src
            dstv[(size_t)(i0 + r1) * NHEADS + hd] = dv;  // everyone needs dst
        }
    }

    cg::this_grid().sync();   // all g rows + dstv visible device-wide

    // ================= Stage 2: fused attention (R4 structure) =================
    const int h  = tid & 7;
    const int js = tid >> 3;              // 0..31

    // ---- Phase A1: ev = adj ? exp(s) : 0 into LDS; zs partial ----
    float zs[2] = {0.f, 0.f};
#pragma unroll
    for (int r = 0; r < 2; r++) {
        const int4   a  = ((const int4*)  adj)[(size_t)(i0 + r) * (NNODES/4) + tid];
        const float4 sv = ((const float4*)s  )[(size_t)(i0 + r) * (NNODES/4) + tid];
        float4 e4;
        e4.x = a.x ? __expf(sv.x) : 0.f;
        e4.y = a.y ? __expf(sv.y) : 0.f;
        e4.z = a.z ? __expf(sv.z) : 0.f;
        e4.w = a.w ? __expf(sv.w) : 0.f;
        ((float4*)evL[r])[tid] = e4;
        zs[r] += e4.x + e4.y + e4.z + e4.w;
    }
    const float sH[2] = { sh_src[0][h], sh_src[1][h] };
    __syncthreads();

    // ---- Phase A2: ze[r][h] = sum over unmasked j of exp(lrelu(src+dst)) ----
    float ze[2] = {0.f, 0.f};
#pragma unroll 4
    for (int t = 0; t < 32; t++) {
        const int j = t * 32 + js;
        const float d = dstv[j * NHEADS + h];
#pragma unroll
        for (int r = 0; r < 2; r++) {
            float e = sH[r] + d;
            e = e > 0.f ? e : NEG_SLOPE * e;
            const float x = __expf(e);
            ze[r] += (evL[r][j] != 0.f) ? x : 0.f;
        }
    }
#pragma unroll
    for (int off = 8; off <= 32; off <<= 1)
#pragma unroll
        for (int r = 0; r < 2; r++) ze[r] += __shfl_xor(ze[r], off, 64);
#pragma unroll
    for (int off = 1; off <= 32; off <<= 1)
#pragma unroll
        for (int r = 0; r < 2; r++) zs[r] += __shfl_xor(zs[r], off, 64);
    if (lane < NHEADS) { zeA[wv][lane][0] = ze[0]; zeA[wv][lane][1] = ze[1]; }
    if (lane == 0)     { zsA[wv][0] = zs[0]; zsA[wv][1] = zs[1]; }
    __syncthreads();
    if (tid < 16) {
        const int hh = tid & 7, rr = tid >> 3;
        statE[rr][hh] = 1.f / (zeA[0][hh][rr] + zeA[1][hh][rr] +
                               zeA[2][hh][rr] + zeA[3][hh][rr]);
    } else if (tid < 18) {
        const int rr = tid - 16;
        statS[rr] = 1.f / (zsA[0][rr] + zsA[1][rr] + zsA[2][rr] + zsA[3][rr]);
    }
    __syncthreads();
    const float ize[2] = { statE[0][h], statE[1][h] };
    const float izs[2] = { statS[0],    statS[1]    };

    // ---- Phase B: w private, FMA g rows into registers ----
    float acc[2][16];
#pragma unroll
    for (int r = 0; r < 2; r++)
#pragma unroll
        for (int f = 0; f < 16; f++) acc[r][f] = 0.f;
    float zt[2] = {0.f, 0.f};

#pragma unroll 2
    for (int t = 0; t < 32; t++) {
        const int j = t * 32 + js;
        const float d = dstv[j * NHEADS + h];
        const float4* gj = (const float4*)(g + (size_t)j * DIM + h * NHID);
        const float4 g0 = gj[0], g1 = gj[1], g2 = gj[2], g3 = gj[3];
#pragma unroll
        for (int r = 0; r < 2; r++) {
            const float ev = evL[r][j];
            float e = sH[r] + d;
            e = e > 0.f ? e : NEG_SLOPE * e;
            const float x   = __expf(e);
            const float arg = (ev != 0.f) ? fmaf(x, ize[r], ev * izs[r]) : 0.f;
            const float w   = __expf(arg);      // exp(0)=1 at masked positions
            zt[r] += w;
            acc[r][0]  = fmaf(w, g0.x, acc[r][0]);
            acc[r][1]  = fmaf(w, g0.y, acc[r][1]);
            acc[r][2]  = fmaf(w, g0.z, acc[r][2]);
            acc[r][3]  = fmaf(w, g0.w, acc[r][3]);
            acc[r][4]  = fmaf(w, g1.x, acc[r][4]);
            acc[r][5]  = fmaf(w, g1.y, acc[r][5]);
            acc[r][6]  = fmaf(w, g1.z, acc[r][6]);
            acc[r][7]  = fmaf(w, g1.w, acc[r][7]);
            acc[r][8]  = fmaf(w, g2.x, acc[r][8]);
            acc[r][9]  = fmaf(w, g2.y, acc[r][9]);
            acc[r][10] = fmaf(w, g2.z, acc[r][10]);
            acc[r][11] = fmaf(w, g2.w, acc[r][11]);
            acc[r][12] = fmaf(w, g3.x, acc[r][12]);
            acc[r][13] = fmaf(w, g3.y, acc[r][13]);
            acc[r][14] = fmaf(w, g3.z, acc[r][14]);
            acc[r][15] = fmaf(w, g3.w, acc[r][15]);
        }
    }

    // ---- Epilogue: reduce over js-in-wave (lane bits 3..5), then 4 waves ----
#pragma unroll
    for (int off = 8; off <= 32; off <<= 1)
#pragma unroll
        for (int r = 0; r < 2; r++) {
#pragma unroll
            for (int f = 0; f < 16; f++)
                acc[r][f] += __shfl_xor(acc[r][f], off, 64);
            zt[r] += __shfl_xor(zt[r], off, 64);
        }
    if (lane < NHEADS) {
#pragma unroll
        for (int r = 0; r < 2; r++) {
#pragma unroll
            for (int f = 0; f < 16; f++) redO[wv][r][lane][f] = acc[r][f];
            ztA[wv][r][lane] = zt[r];
        }
    }
    __syncthreads();
    {
        const int rr = tid >> 7;
        const int hf = tid & 127;
        const int oh = hf >> 4;
        const int f  = hf & 15;
        const float v  = redO[0][rr][oh][f] + redO[1][rr][oh][f] +
                         redO[2][rr][oh][f] + redO[3][rr][oh][f];
        const float zq = ztA[0][rr][oh] + ztA[1][rr][oh] +
                         ztA[2][rr][oh] + ztA[3][rr][oh];
        out[(size_t)(i0 + rr) * DIM + hf] = v / zq;
    }
}

extern "C" void kernel_launch(void* const* d_in, const int* in_sizes, int n_in,
                              void* d_out, int out_size, void* d_ws, size_t ws_size,
                              hipStream_t stream) {
    const float* hfeat  = (const float*)d_in[0];
    const int*   adj    = (const int*)  d_in[1];
    const float* s      = (const float*)d_in[2];
    const float* W      = (const float*)d_in[3];
    const float* attn_w = (const float*)d_in[4];
    float* out  = (float*)d_out;
    float* g    = (float*)d_ws;                      // 1024*128
    float* dstv = g + (size_t)NNODES * DIM;          // 1024*8

    void* args[] = { (void*)&hfeat, (void*)&adj, (void*)&s, (void*)&W,
                     (void*)&attn_w, (void*)&g, (void*)&dstv, (void*)&out };
    hipLaunchCooperativeKernel((const void*)gat_kernel,
                               dim3(NNODES / 2), dim3(256), args, 0, stream);
}

// Round 8
// 87.433 us; speedup vs baseline: 1.8076x; 1.8076x over previous
//
#include <hip/hip_runtime.h>

#define NNODES 1024
#define NHEADS 8
#define NHID 16
#define DIM 128            // NHEADS * NHID
#define NEG_SLOPE 0.2f

// K1: g = h @ W^T ; src[i,h] = g[i,h,:]·a_src ; dst[i,h] = g[i,h,:]·a_dst
__global__ __launch_bounds__(128) void proj_kernel(
    const float* __restrict__ h, const float* __restrict__ W,
    const float* __restrict__ attn_w,
    float* __restrict__ g, float* __restrict__ srcv, float* __restrict__ dstv)
{
    const int i = blockIdx.x;
    const int o = threadIdx.x;
    __shared__ float hs[DIM];
    hs[o] = h[(size_t)i * DIM + o];
    __syncthreads();
    const float4* hv = (const float4*)hs;
    const float4* wv = (const float4*)(W + (size_t)o * DIM);
    float acc = 0.f;
#pragma unroll
    for (int k = 0; k < DIM / 4; k++) {
        float4 a = hv[k]; float4 b = wv[k];
        acc = fmaf(a.x, b.x, fmaf(a.y, b.y, fmaf(a.z, b.z, fmaf(a.w, b.w, acc))));
    }
    g[(size_t)i * DIM + o] = acc;
    const int f  = o & (NHID - 1);
    const int hd = o >> 4;
    float sv = acc * attn_w[f];
    float dv = acc * attn_w[NHID + f];
#pragma unroll
    for (int off = 8; off > 0; off >>= 1) {
        sv += __shfl_xor(sv, off, 64);
        dv += __shfl_xor(dv, off, 64);
    }
    if (f == 0) { srcv[i * NHEADS + hd] = sv; dstv[i * NHEADS + hd] = dv; }
}

// K2: one block per 2 rows. Phase B remapped to (js,h,q): each thread owns one
// float4 of a head row -> g loads are 16-line minimal; w computed once per
// 4-j group per q-lane and broadcast via __shfl.
__global__ __launch_bounds__(256, 2) void fused_kernel(
    const int* __restrict__ adj, const float* __restrict__ s,
    const float* __restrict__ g, const float* __restrict__ srcv,
    const float* __restrict__ dstv, float* __restrict__ out)
{
    const int i0   = blockIdx.x * 2;
    const int tid  = threadIdx.x;
    const int lane = tid & 63;
    const int wv   = tid >> 6;            // wave 0..3
    // Phase-A2 mapping
    const int hA   = tid & 7;
    const int jsA  = tid >> 3;            // 0..31
    // Phase-B mapping: tid = jsB*32 + hB*4 + qB
    const int qB   = tid & 3;
    const int hB   = (tid >> 2) & 7;
    const int jsB  = tid >> 5;            // 0..7

    __shared__ float evL[2][NNODES];      // 8 KB
    __shared__ float dstL[NNODES * NHEADS]; // 32 KB staged dstv
    __shared__ float sh_src[2][NHEADS];
    __shared__ float zeA[4][NHEADS][2];
    __shared__ float zsA[4][2];
    __shared__ float statE[2][NHEADS];
    __shared__ float statS[2];
    __shared__ float redO[4][2][NHEADS][4][4];  // 4 KB
    __shared__ float ztA[4][2][NHEADS];

    // ---- Phase A1: ev = adj ? exp(s) : 0 into LDS; zs partial; stage dstv ----
    float zs[2] = {0.f, 0.f};
#pragma unroll
    for (int r = 0; r < 2; r++) {
        const int4   a  = ((const int4*)  adj)[(size_t)(i0 + r) * (NNODES/4) + tid];
        const float4 sv = ((const float4*)s  )[(size_t)(i0 + r) * (NNODES/4) + tid];
        float4 e4;
        e4.x = a.x ? __expf(sv.x) : 0.f;
        e4.y = a.y ? __expf(sv.y) : 0.f;
        e4.z = a.z ? __expf(sv.z) : 0.f;
        e4.w = a.w ? __expf(sv.w) : 0.f;
        ((float4*)evL[r])[tid] = e4;
        zs[r] += e4.x + e4.y + e4.z + e4.w;
    }
    {
        const float4* dv4 = (const float4*)dstv;
        float4* dl4 = (float4*)dstL;
#pragma unroll
        for (int k = 0; k < 8; k++) dl4[k * 256 + tid] = dv4[k * 256 + tid];
        if (tid < 16) sh_src[tid >> 3][tid & 7] =
            srcv[(size_t)(i0 + (tid >> 3)) * NHEADS + (tid & 7)];
    }
    __syncthreads();

    // ---- Phase A2: ze[r][h] over unmasked j ----
    float ze[2] = {0.f, 0.f};
    {
        const float sHA[2] = { sh_src[0][hA], sh_src[1][hA] };
#pragma unroll 4
        for (int t = 0; t < 32; t++) {
            const int j = t * 32 + jsA;
            const float d = dstL[j * NHEADS + hA];
#pragma unroll
            for (int r = 0; r < 2; r++) {
                float e = sHA[r] + d;
                e = e > 0.f ? e : NEG_SLOPE * e;
                const float x = __expf(e);
                ze[r] += (evL[r][j] != 0.f) ? x : 0.f;
            }
        }
    }
#pragma unroll
    for (int off = 8; off <= 32; off <<= 1)
#pragma unroll
        for (int r = 0; r < 2; r++) ze[r] += __shfl_xor(ze[r], off, 64);
#pragma unroll
    for (int off = 1; off <= 32; off <<= 1)
#pragma unroll
        for (int r = 0; r < 2; r++) zs[r] += __shfl_xor(zs[r], off, 64);
    if (lane < NHEADS) { zeA[wv][lane][0] = ze[0]; zeA[wv][lane][1] = ze[1]; }
    if (lane == 0)     { zsA[wv][0] = zs[0]; zsA[wv][1] = zs[1]; }
    __syncthreads();
    if (tid < 16) {
        const int hh = tid & 7, rr = tid >> 3;
        statE[rr][hh] = 1.f / (zeA[0][hh][rr] + zeA[1][hh][rr] +
                               zeA[2][hh][rr] + zeA[3][hh][rr]);
    } else if (tid < 18) {
        const int rr = tid - 16;
        statS[rr] = 1.f / (zsA[0][rr] + zsA[1][rr] + zsA[2][rr] + zsA[3][rr]);
    }
    __syncthreads();

    // ---- Phase B ----
    const float ize[2] = { statE[0][hB], statE[1][hB] };
    const float izs[2] = { statS[0],     statS[1]     };
    const float sHB[2] = { sh_src[0][hB], sh_src[1][hB] };
    const int   base   = lane & ~3;       // q-group leader for shfl

    float acc[2][4] = {{0.f,0.f,0.f,0.f},{0.f,0.f,0.f,0.f}};
    float zt[2] = {0.f, 0.f};
    const float4* g4 = (const float4*)g;

#pragma unroll 2
    for (int tg = 0; tg < 32; tg++) {
        // this lane's w-j: k = qB within the 4-j group
        const int jw = (tg * 4 + qB) * 8 + jsB;
        const float d = dstL[jw * NHEADS + hB];
        float w[2];
#pragma unroll
        for (int r = 0; r < 2; r++) {
            float e = sHB[r] + d;
            e = e > 0.f ? e : NEG_SLOPE * e;
            const float x  = __expf(e);
            const float ev = evL[r][jw];
            const float arg = (ev != 0.f) ? fmaf(x, ize[r], ev * izs[r]) : 0.f;
            w[r] = __expf(arg);           // exp(0)=1 at masked positions
            zt[r] += w[r];
        }
#pragma unroll
        for (int k = 0; k < 4; k++) {
            const int j = (tg * 4 + k) * 8 + jsB;
            const float4 gv = g4[(size_t)j * 32 + hB * 4 + qB];
            const float w0 = __shfl(w[0], base + k, 64);
            const float w1 = __shfl(w[1], base + k, 64);
            acc[0][0] = fmaf(w0, gv.x, acc[0][0]);
            acc[0][1] = fmaf(w0, gv.y, acc[0][1]);
            acc[0][2] = fmaf(w0, gv.z, acc[0][2]);
            acc[0][3] = fmaf(w0, gv.w, acc[0][3]);
            acc[1][0] = fmaf(w1, gv.x, acc[1][0]);
            acc[1][1] = fmaf(w1, gv.y, acc[1][1]);
            acc[1][2] = fmaf(w1, gv.z, acc[1][2]);
            acc[1][3] = fmaf(w1, gv.w, acc[1][3]);
        }
    }

    // ---- Epilogue ----
    // acc: reduce over jsB-in-wave only (bit 5); q/h stay distinct
#pragma unroll
    for (int r = 0; r < 2; r++)
#pragma unroll
        for (int m = 0; m < 4; m++) acc[r][m] += __shfl_xor(acc[r][m], 32, 64);
    // zt: reduce over q (bits 0,1) and jsB-in-wave (bit 5)
#pragma unroll
    for (int r = 0; r < 2; r++) {
        zt[r] += __shfl_xor(zt[r], 1, 64);
        zt[r] += __shfl_xor(zt[r], 2, 64);
        zt[r] += __shfl_xor(zt[r], 32, 64);
    }
    if (lane < 32) {
#pragma unroll
        for (int r = 0; r < 2; r++)
            *(float4*)&redO[wv][r][hB][qB][0] =
                make_float4(acc[r][0], acc[r][1], acc[r][2], acc[r][3]);
        if ((lane & 3) == 0) { ztA[wv][0][hB] = zt[0]; ztA[wv][1][hB] = zt[1]; }
    }
    __syncthreads();
    {
        const int rr = tid >> 7;
        const int hf = tid & 127;
        const int oh = hf >> 4;
        const int qq = (hf >> 2) & 3;
        const int mm = hf & 3;
        const float v  = redO[0][rr][oh][qq][mm] + redO[1][rr][oh][qq][mm] +
                         redO[2][rr][oh][qq][mm] + redO[3][rr][oh][qq][mm];
        const float zq = ztA[0][rr][oh] + ztA[1][rr][oh] +
                         ztA[2][rr][oh] + ztA[3][rr][oh];
        out[(size_t)(i0 + rr) * DIM + hf] = v / zq;
    }
}

extern "C" void kernel_launch(void* const* d_in, const int* in_sizes, int n_in,
                              void* d_out, int out_size, void* d_ws, size_t ws_size,
                              hipStream_t stream) {
    const float* h      = (const float*)d_in[0];
    const int*   adj    = (const int*)  d_in[1];
    const float* s      = (const float*)d_in[2];
    const float* W      = (const float*)d_in[3];
    const float* attn_w = (const float*)d_in[4];
    float* out = (float*)d_out;

    float* g    = (float*)d_ws;                      // 1024*128
    float* srcv = g    + (size_t)NNODES * DIM;       // 1024*8
    float* dstv = srcv + (size_t)NNODES * NHEADS;    // 1024*8

    proj_kernel <<<NNODES, DIM, 0, stream>>>(h, W, attn_w, g, srcv, dstv);
    fused_kernel<<<NNODES / 2, 256, 0, stream>>>(adj, s, g, srcv, dstv, out);
}